// Round 16
// baseline (241.420 us; speedup 1.0000x reference)
//
#include <hip/hip_runtime.h>
#include <hip/hip_fp16.h>

#define SEQ 256
#define NPOS 1024
#define NSPLIT 4

typedef __attribute__((ext_vector_type(8))) short bf16x8;
typedef __attribute__((ext_vector_type(4))) float f32x4;

__device__ __forceinline__ unsigned short f2bf(float x) {
  unsigned int u = __float_as_uint(x);
  return (unsigned short)((u + 0x7FFFu + ((u >> 16) & 1u)) >> 16);
}

// DPP cross-lane add helpers (VALU pipe)
template <int CTRL>
__device__ __forceinline__ float dpp_add(float x) {
  return x + __int_as_float(__builtin_amdgcn_update_dpp(
                 0, __float_as_int(x), CTRL, 0xF, 0xF, true));
}
#define DPP_XOR1 0xB1
#define DPP_XOR2 0x4E
#define DPP_ROR4 0x124
#define DPP_ROR8 0x128
__device__ __forceinline__ float swz_xor16(float x) {
  return __int_as_float(__builtin_amdgcn_ds_swizzle(__float_as_int(x), 0x401F));
}
__device__ __forceinline__ float bperm(int addr, float x) {
  return __int_as_float(__builtin_amdgcn_ds_bpermute(addr, __float_as_int(x)));
}

// ---------------- prep: squash + LN -> emb0 (fp32) + emb0b (bf16)
__global__ __launch_bounds__(256) void prep_kernel(
    const float* __restrict__ x, const float* __restrict__ g,
    const float* __restrict__ be, float* __restrict__ emb0,
    unsigned short* __restrict__ emb0b) {
  const int pos = blockIdx.x;
  const int t = threadIdx.x;
  float v = x[(size_t)pos * 256 + t];
  float sn = v * v;
  sn += __shfl_xor(sn, 1); sn += __shfl_xor(sn, 2);
  sn += __shfl_xor(sn, 4); sn += __shfl_xor(sn, 8);
  float e = v * (sn / (1.f + sn)) * rsqrtf(sn + 1e-9f);
  __shared__ float red[2][4];
  float s1 = e, s2 = e * e;
  for (int m = 1; m < 64; m <<= 1) { s1 += __shfl_xor(s1, m); s2 += __shfl_xor(s2, m); }
  if ((t & 63) == 0) { red[0][t >> 6] = s1; red[1][t >> 6] = s2; }
  __syncthreads();
  float tot = 0.f, tot2 = 0.f;
#pragma unroll
  for (int i = 0; i < 4; i++) { tot += red[0][i]; tot2 += red[1][i]; }
  float mean = tot * (1.f / 256.f);
  float var = tot2 * (1.f / 256.f) - mean * mean;
  float val = g[t] * (e - mean) * rsqrtf(var + 1e-3f) + be[t];
  emb0[(size_t)pos * 256 + t] = val;
  emb0b[(size_t)pos * 256 + t] = f2bf(val);
}

// ---------------- Bt builder (vectorized x8): Bt[od][k] from W; 8 contiguous
// k share one (w,h) slice (ESTR%8==0, 16%8==0) -> 2x float4 read, 16B store.
template <int K, int ESTR, int IN_H>
__global__ __launch_bounds__(256) void conv_bt(
    const float* __restrict__ W, unsigned short* __restrict__ Bt) {
  int idx = blockIdx.x * 256 + threadIdx.x;
  if (idx >= 512 * (K / 8)) return;
  int od = idx / (K / 8);
  int k8 = (idx - od * (K / 8)) * 8;
  int w = k8 / ESTR;
  int hl = k8 - w * ESTR;
  int h = hl >> 4, l0 = hl & 15;
  const float* src = W + (size_t)(w * IN_H + h) * 8192 + od * 16 + l0;
  float4 a = *(const float4*)src;
  float4 b = *(const float4*)(src + 4);
  uint4 v;
  v.x = (unsigned)f2bf(a.x) | ((unsigned)f2bf(a.y) << 16);
  v.y = (unsigned)f2bf(a.z) | ((unsigned)f2bf(a.w) << 16);
  v.z = (unsigned)f2bf(b.x) | ((unsigned)f2bf(b.y) << 16);
  v.w = (unsigned)f2bf(b.z) | ((unsigned)f2bf(b.w) << 16);
  *(uint4*)(Bt + (size_t)od * K + k8) = v;
}

// ---------------- bias sum (parallel): grid(4) x 512thr; 4-way i-split + LDS
template <int INH>
__global__ __launch_bounds__(512) void bias_sum(
    const float* __restrict__ Bi, float* __restrict__ bias) {
  __shared__ float lds[4][128];
  const int odl = threadIdx.x & 127;
  const int part = threadIdx.x >> 7;
  const int od = blockIdx.x * 128 + odl;
  float s = 0.f;
  for (int i = part; i < INH; i += 4) s += Bi[(size_t)i * 512 + od];
  lds[part][odl] = s;
  __syncthreads();
  if (part == 0) bias[od] = lds[0][odl] + lds[1][odl] + lds[2][odl] + lds[3][odl];
}

// ---------------- sa_gemm v3: barrier-free, LDS-free, K-SPLIT x4 for
// occupancy (r15's 512-block grid = 2 blocks/CU left the dependent-MFMA
// chain latency-exposed). Each split writes its own partial buffer
// sAp[split][p][od] (deterministic, no atomics); split 0 adds bias.
// Wave = 16p x 16od tile; A-fragment direct from global embB (k-octets never
// cross window boundaries, ESTR%8==0); B from Bt. Operands L2-hot.
template <int K, int ESTR>
__global__ __launch_bounds__(256) void sa_gemm(
    const unsigned short* __restrict__ embB, const unsigned short* __restrict__ Bt,
    const float* __restrict__ bias, float* __restrict__ sAp) {
  constexpr int KC = K / NSPLIT;
  const int pt = blockIdx.x;      // 16 positions per tile
  const int og = blockIdx.y;      // 8 od-groups of 64
  const int sp = blockIdx.z;      // K-split index
  const int t = threadIdx.x;      // 256
  const int wv = t >> 6, l = t & 63;
  const int od0 = og * 64 + wv * 16;
  const int fr = l & 15;
  const int koct = (l >> 4) * 8;
  const int pg = pt * 16 + fr;
  const int sbase = pg & 255;
  const unsigned short* bptr = Bt + (size_t)(od0 + fr) * K + koct;
  f32x4 acc = {0.f, 0.f, 0.f, 0.f};
  const int kbeg = sp * KC;
#pragma unroll 4
  for (int k0 = kbeg; k0 < kbeg + KC; k0 += 32) {
    const int k = k0 + koct;
    const int w = k / ESTR;            // ESTR pow2 -> shift
    const int c = k - w * ESTR;
    const int s = sbase + w - 2;
    bf16x8 af = {0, 0, 0, 0, 0, 0, 0, 0};
    if (s >= 0 && s < SEQ)
      af = *(const bf16x8*)(embB + (size_t)(pg + w - 2) * ESTR + c);
    bf16x8 bf = *(const bf16x8*)(bptr + k0);
    acc = __builtin_amdgcn_mfma_f32_16x16x32_bf16(af, bf, acc, 0, 0, 0);
  }
  const float bs = (sp == 0) ? bias[od0 + fr] : 0.f;
  float* dst = sAp + (size_t)sp * NPOS * 512;
#pragma unroll
  for (int j = 0; j < 4; j++) {
    int r = (l >> 4) * 4 + j;
    dst[(size_t)(pt * 16 + r) * 512 + od0 + fr] = acc[j] + bs;
  }
}

// ---------------- einsum (r12 PT=64 version, half2 stores)
template <int INH, int IN_H, int ESTR>
__global__ __launch_bounds__(512) void einsum_kernel(
    const float* __restrict__ W, const float* __restrict__ Bi,
    const float* __restrict__ emb, __half* __restrict__ u, int pos0) {
  constexpr int PT = 64;
  const int i = blockIdx.x;
  const int pt = blockIdx.y;
  const int t = threadIdx.x;
  const int c = t & 255;
  const int ph = t >> 8;
  const int w = i / IN_H, h = i % IN_H;
  __shared__ float W_lds[16][512];
  __shared__ float we_lds[PT][16];
  const float* Wi = W + (size_t)i * 8192;
#pragma unroll
  for (int j = 0; j < 4; j++) {
    const float4 wv = *(const float4*)(Wi + (size_t)t * 16 + j * 4);
    W_lds[j * 4 + 0][t] = wv.x; W_lds[j * 4 + 1][t] = wv.y;
    W_lds[j * 4 + 2][t] = wv.z; W_lds[j * 4 + 3][t] = wv.w;
  }
#pragma unroll
  for (int j = 0; j < PT * 16 / 512; j++) {
    int idx = t + j * 512;
    int p = idx >> 4, l = idx & 15;
    int pos = pos0 + pt * PT + p;
    int s = pos & 255;
    int sr = s + w - 2;
    float val = 0.f;
    if (sr >= 0 && sr < SEQ) val = emb[(size_t)(pos + (w - 2)) * ESTR + h * 16 + l];
    we_lds[p][l] = val;
  }
  __syncthreads();
  float wr0[16], wr1[16];
#pragma unroll
  for (int l = 0; l < 16; l++) { wr0[l] = W_lds[l][2 * c]; wr1[l] = W_lds[l][2 * c + 1]; }
  const float b0 = Bi[(size_t)i * 512 + 2 * c];
  const float b1 = Bi[(size_t)i * 512 + 2 * c + 1];
  __half* ub = u + ((size_t)(pt * PT + ph * 32) * INH + i) * 512 + 2 * c;
#pragma unroll 4
  for (int p2 = 0; p2 < 32; p2++) {
    const int p = ph * 32 + p2;
    float a0 = b0, a1 = b1;
#pragma unroll
    for (int l = 0; l < 16; l++) {
      float e = we_lds[p][l];
      a0 = fmaf(wr0[l], e, a0);
      a1 = fmaf(wr1[l], e, a1);
    }
    *(__half2*)(ub + (size_t)p2 * INH * 512) = __floats2half2_rn(a0, a1);
  }
}

// ---------------- routing: pass A read eliminated (sA precomputed, read as
// 4 K-split partials). u_hat streamed 2x -> at 6.2 TB/s combined delivery
// ceiling (measured r15). DPP softmax; VGPR<=64 class.
template <int INH, bool MASK, bool FINAL>
__global__ __launch_bounds__(512) void route_kernel(
    const __half* __restrict__ u, const float* __restrict__ sAp,
    const float* __restrict__ g, const float* __restrict__ be,
    const float* __restrict__ g_o, const float* __restrict__ b_o,
    float* __restrict__ outp, unsigned short* __restrict__ outb, int pos0) {
  constexpr int ROWS = INH / 8;
  const int w = threadIdx.x >> 6;
  const int l = threadIdx.x & 63;
  const int o = l >> 1;
  const int p = blockIdx.x;
  const int posg = pos0 + p;
  const int xaddr = ((l ^ 32) << 2);
  const __half* ug = u + (size_t)p * INH * 512 + (size_t)w * ROWS * 512 + l * 8;

  __shared__ float red_s[8][512];

#define UNPACK(q, f)                                            \
  {                                                             \
    float2 f0 = __half22float2(*(const __half2*)&(q).x);        \
    float2 f1 = __half22float2(*(const __half2*)&(q).y);        \
    float2 f2 = __half22float2(*(const __half2*)&(q).z);        \
    float2 f3 = __half22float2(*(const __half2*)&(q).w);        \
    f[0] = f0.x; f[1] = f0.y; f[2] = f1.x; f[3] = f1.y;         \
    f[4] = f2.x; f[5] = f2.y; f[6] = f3.x; f[7] = f3.y;         \
  }

  // ---- iter 1 from precomputed sA (sum of 4 K-split partials, L2-hot)
  float s8[8];
#pragma unroll
  for (int k = 0; k < 8; k++) s8[k] = 0.f;
#pragma unroll
  for (int spx = 0; spx < NSPLIT; spx++) {
    const float* spp = sAp + ((size_t)spx * NPOS + posg) * 512 + l * 8;
    float4 a = *(const float4*)spp;
    float4 b = *(const float4*)(spp + 4);
    s8[0] += a.x; s8[1] += a.y; s8[2] += a.z; s8[3] += a.w;
    s8[4] += b.x; s8[5] += b.y; s8[6] += b.z; s8[7] += b.w;
  }
  const float c1 = MASK ? (o == 0 ? 0.f : (1.f / 31.f)) : (1.f / 32.f);
  float vd[8], vout[8];
  {
    float sn = 0.f;
#pragma unroll
    for (int k = 0; k < 8; k++) { s8[k] *= c1; sn += s8[k] * s8[k]; }
    sn = dpp_add<DPP_XOR1>(sn);
    float f = (sn / (1.f + sn)) * rsqrtf(sn + 1e-9f);
#pragma unroll
    for (int k = 0; k < 8; k++) vd[k] = s8[k] * f;  // vd = v1
  }

  // ---- passes B, C (iters 2, 3); pass C dots against v1+v2 (b telescopes)
#pragma unroll
  for (int iter = 0; iter < 2; iter++) {
    float sacc[8];
#pragma unroll
    for (int k = 0; k < 8; k++) sacc[k] = 0.f;
#pragma unroll 2
    for (int r = 0; r < ROWS; r++) {
      uint4 q = *(const uint4*)(ug + (size_t)r * 512);
      float u8[8];
      UNPACK(q, u8);
      float a = u8[0] * vd[0];
#pragma unroll
      for (int k = 1; k < 8; k++) a = fmaf(u8[k], vd[k], a);
      a = dpp_add<DPP_XOR1>(a);
      float e = (MASK && o == 0) ? 0.f : __expf(a);
      float ss = dpp_add<DPP_XOR1>(e);
      ss = dpp_add<DPP_XOR2>(ss);
      ss = dpp_add<DPP_ROR4>(ss);
      ss = dpp_add<DPP_ROR8>(ss);
      ss += swz_xor16(ss);
      ss += bperm(xaddr, ss);
      float c = __fdividef(e + e, ss);
#pragma unroll
      for (int k = 0; k < 8; k++) sacc[k] = fmaf(c, u8[k], sacc[k]);
    }
    __syncthreads();
    *(float4*)&red_s[w][l * 8]     = make_float4(sacc[0], sacc[1], sacc[2], sacc[3]);
    *(float4*)&red_s[w][l * 8 + 4] = make_float4(sacc[4], sacc[5], sacc[6], sacc[7]);
    __syncthreads();
#pragma unroll
    for (int k = 0; k < 8; k++) sacc[k] = 0.f;
#pragma unroll
    for (int w2 = 0; w2 < 8; w2++) {
      float4 a = *(const float4*)&red_s[w2][l * 8];
      float4 b = *(const float4*)&red_s[w2][l * 8 + 4];
      sacc[0] += a.x; sacc[1] += a.y; sacc[2] += a.z; sacc[3] += a.w;
      sacc[4] += b.x; sacc[5] += b.y; sacc[6] += b.z; sacc[7] += b.w;
    }
    float sn = 0.f;
#pragma unroll
    for (int k = 0; k < 8; k++) sn += sacc[k] * sacc[k];
    sn = dpp_add<DPP_XOR1>(sn);
    float f = (sn / (1.f + sn)) * rsqrtf(sn + 1e-9f);
#pragma unroll
    for (int k = 0; k < 8; k++) {
      vout[k] = sacc[k] * f;
      vd[k] += vout[k];
    }
  }

  // ---- epilogue: LN over 512
  float s1 = 0.f, s2 = 0.f;
#pragma unroll
  for (int k = 0; k < 8; k++) { s1 += vout[k]; s2 += vout[k] * vout[k]; }
  for (int m = 1; m < 64; m <<= 1) { s1 += __shfl_xor(s1, m); s2 += __shfl_xor(s2, m); }
  float mean = s1 * (1.f / 512.f);
  float var = s2 * (1.f / 512.f) - mean * mean;
  float rstd = rsqrtf(var + 1e-3f);
  const float4 g0 = *(const float4*)(g + 8 * l);
  const float4 g1 = *(const float4*)(g + 8 * l + 4);
  const float4 be0 = *(const float4*)(be + 8 * l);
  const float4 be1 = *(const float4*)(be + 8 * l + 4);
  float nv[8];
  nv[0] = g0.x * (vout[0] - mean) * rstd + be0.x;
  nv[1] = g0.y * (vout[1] - mean) * rstd + be0.y;
  nv[2] = g0.z * (vout[2] - mean) * rstd + be0.z;
  nv[3] = g0.w * (vout[3] - mean) * rstd + be0.w;
  nv[4] = g1.x * (vout[4] - mean) * rstd + be1.x;
  nv[5] = g1.y * (vout[5] - mean) * rstd + be1.y;
  nv[6] = g1.z * (vout[6] - mean) * rstd + be1.z;
  nv[7] = g1.w * (vout[7] - mean) * rstd + be1.w;

  if (!FINAL) {
    if (w == 0) {
      float4 w0 = {nv[0], nv[1], nv[2], nv[3]};
      float4 w1 = {nv[4], nv[5], nv[6], nv[7]};
      float* op = outp + (size_t)posg * 512 + 8 * l;
      *(float4*)op = w0; *(float4*)(op + 4) = w1;
      uint4 bb;
      bb.x = (unsigned)f2bf(nv[0]) | ((unsigned)f2bf(nv[1]) << 16);
      bb.y = (unsigned)f2bf(nv[2]) | ((unsigned)f2bf(nv[3]) << 16);
      bb.z = (unsigned)f2bf(nv[4]) | ((unsigned)f2bf(nv[5]) << 16);
      bb.w = (unsigned)f2bf(nv[6]) | ((unsigned)f2bf(nv[7]) << 16);
      *(uint4*)(outb + (size_t)posg * 512 + 8 * l) = bb;
    }
  } else {
    float l2 = 0.f;
#pragma unroll
    for (int k = 0; k < 8; k++) l2 += nv[k] * nv[k];
    l2 = dpp_add<DPP_XOR1>(l2);
    float len = sqrtf(l2 + 1e-9f);
    float a1 = len, a2 = len * len;
    for (int m = 1; m < 64; m <<= 1) { a1 += __shfl_xor(a1, m); a2 += __shfl_xor(a2, m); }
    float mm = a1 * (1.f / 64.f);
    float vv = a2 * (1.f / 64.f) - mm * mm;
    if (w == 0 && (l & 1) == 0)
      outp[(size_t)posg * 32 + o] = g_o[o] * (len - mm) * rsqrtf(vv + 1e-3f) + b_o[o];
  }
#undef UNPACK
}

extern "C" void kernel_launch(void* const* d_in, const int* in_sizes, int n_in,
                              void* d_out, int out_size, void* d_ws, size_t ws_size,
                              hipStream_t stream) {
  const float* x    = (const float*)d_in[0];
  const float* W0   = (const float*)d_in[1];
  const float* B0   = (const float*)d_in[2];
  const float* W1   = (const float*)d_in[3];
  const float* B1   = (const float*)d_in[4];
  const float* g_i  = (const float*)d_in[5];
  const float* b_i  = (const float*)d_in[6];
  const float* g_m0 = (const float*)d_in[7];
  const float* b_m0 = (const float*)d_in[8];
  const float* g_m1 = (const float*)d_in[9];
  const float* b_m1 = (const float*)d_in[10];
  const float* g_o  = (const float*)d_in[11];
  const float* b_o  = (const float*)d_in[12];
  float* out = (float*)d_out;

  char* ws = (char*)d_ws;
  float* emb0            = (float*)(ws);                      // 1 MB
  float* emb1            = (float*)(ws + 1048576);            // 2 MB
  unsigned short* emb0b  = (unsigned short*)(ws + 3145728);   // 0.5 MB
  unsigned short* emb1b  = (unsigned short*)(ws + 3670016);   // 1 MB
  float* sAp0            = (float*)(ws + 4718592);            // 8 MB (4 partials)
  float* sAp1            = (float*)(ws + 13107200);           // 8 MB
  unsigned short* Bt0    = (unsigned short*)(ws + 21495808);  // 1.25 MB
  unsigned short* Bt1    = (unsigned short*)(ws + 22806528);  // 2.5 MB
  float* bias0           = (float*)(ws + 25427968);           // 2 KB
  float* bias1           = (float*)(ws + 25430016);           // 2 KB
  __half* ubuf           = (__half*)(ws + 25690112);

  size_t avail = ws_size > (size_t)25690112 ? ws_size - 25690112 : 0;
  int chunk = 1024;
  while (chunk > 128 && (size_t)chunk * 163840 > avail) chunk >>= 1;

  prep_kernel<<<NPOS, 256, 0, stream>>>(x, g_i, b_i, emb0, emb0b);
  conv_bt<1280, 256, 16><<<(512 * 160 + 255) / 256, 256, 0, stream>>>(W0, Bt0);
  conv_bt<2560, 512, 32><<<(512 * 320 + 255) / 256, 256, 0, stream>>>(W1, Bt1);
  bias_sum<80><<<4, 512, 0, stream>>>(B0, bias0);
  bias_sum<160><<<4, 512, 0, stream>>>(B1, bias1);
  sa_gemm<1280, 256><<<dim3(64, 8, NSPLIT), 256, 0, stream>>>(emb0b, Bt0, bias0, sAp0);

  for (int p0 = 0; p0 < NPOS; p0 += chunk) {
    int cp = (NPOS - p0 < chunk) ? (NPOS - p0) : chunk;
    einsum_kernel<80, 16, 256><<<dim3(80, cp / 64), 512, 0, stream>>>(W0, B0, emb0, ubuf, p0);
    route_kernel<80, false, false><<<cp, 512, 0, stream>>>(ubuf, sAp0, g_m0, b_m0, nullptr, nullptr, emb1, emb1b, p0);
  }

  sa_gemm<2560, 512><<<dim3(64, 8, NSPLIT), 256, 0, stream>>>(emb1b, Bt1, bias1, sAp1);

  for (int p0 = 0; p0 < NPOS; p0 += chunk) {
    int cp = (NPOS - p0 < chunk) ? (NPOS - p0) : chunk;
    einsum_kernel<160, 32, 512><<<dim3(160, cp / 64), 512, 0, stream>>>(W1, B1, emb1, ubuf, p0);
    route_kernel<160, true, true><<<cp, 512, 0, stream>>>(ubuf, sAp1, g_m1, b_m1, g_o, b_o, out, nullptr, p0);
  }
}

// Round 17
// 216.106 us; speedup vs baseline: 1.1171x; 1.1171x over previous
//
#include <hip/hip_runtime.h>
#include <hip/hip_fp16.h>

#define SEQ 256
#define NPOS 1024

typedef __attribute__((ext_vector_type(8))) short bf16x8;
typedef __attribute__((ext_vector_type(4))) float f32x4;

__device__ __forceinline__ unsigned f2bf(float x) {
  unsigned int u = __float_as_uint(x);
  return (u + 0x7FFFu + ((u >> 16) & 1u)) >> 16;
}

// DPP cross-lane add helpers (VALU pipe)
template <int CTRL>
__device__ __forceinline__ float dpp_add(float x) {
  return x + __int_as_float(__builtin_amdgcn_update_dpp(
                 0, __float_as_int(x), CTRL, 0xF, 0xF, true));
}
#define DPP_XOR1 0xB1
#define DPP_XOR2 0x4E
#define DPP_ROR4 0x124
#define DPP_ROR8 0x128
__device__ __forceinline__ float swz_xor16(float x) {
  return __int_as_float(__builtin_amdgcn_ds_swizzle(__float_as_int(x), 0x401F));
}
__device__ __forceinline__ float bperm(int addr, float x) {
  return __int_as_float(__builtin_amdgcn_ds_bpermute(addr, __float_as_int(x)));
}

// ---------------- prep: squash + LN -> emb0 (fp32) + emb0b (bf16)
__global__ __launch_bounds__(256) void prep_kernel(
    const float* __restrict__ x, const float* __restrict__ g,
    const float* __restrict__ be, float* __restrict__ emb0,
    unsigned short* __restrict__ emb0b) {
  const int pos = blockIdx.x;
  const int t = threadIdx.x;
  float v = x[(size_t)pos * 256 + t];
  float sn = v * v;
  sn += __shfl_xor(sn, 1); sn += __shfl_xor(sn, 2);
  sn += __shfl_xor(sn, 4); sn += __shfl_xor(sn, 8);
  float e = v * (sn / (1.f + sn)) * rsqrtf(sn + 1e-9f);
  __shared__ float red[2][4];
  float s1 = e, s2 = e * e;
  for (int m = 1; m < 64; m <<= 1) { s1 += __shfl_xor(s1, m); s2 += __shfl_xor(s2, m); }
  if ((t & 63) == 0) { red[0][t >> 6] = s1; red[1][t >> 6] = s2; }
  __syncthreads();
  float tot = 0.f, tot2 = 0.f;
#pragma unroll
  for (int i = 0; i < 4; i++) { tot += red[0][i]; tot2 += red[1][i]; }
  float mean = tot * (1.f / 256.f);
  float var = tot2 * (1.f / 256.f) - mean * mean;
  float val = g[t] * (e - mean) * rsqrtf(var + 1e-3f) + be[t];
  emb0[(size_t)pos * 256 + t] = val;
  emb0b[(size_t)pos * 256 + t] = (unsigned short)f2bf(val);
}

// ---------------- conv_btf: build B-operand IN MFMA FRAGMENT ORDER.
// Btf element addr = 8*gid with gid = kc*2048 + odt*64 + fr*4 + koct
// (so writes are perfectly linear). Value = bf16(W[(w*IN_H+h)*8192+od*16+lW])
// for od=odt*16+fr, k=kc*32+koct*8 (+0..7), all 8 k in one (w,h) slice.
template <int K, int ESTR, int IN_H>
__global__ __launch_bounds__(256) void conv_btf(
    const float* __restrict__ W, unsigned short* __restrict__ Btf) {
  int gid = blockIdx.x * 256 + threadIdx.x;
  if (gid >= 512 * (K / 8)) return;
  const int koct = gid & 3;
  const int fr = (gid >> 2) & 15;
  const int odt = (gid >> 6) & 31;
  const int kc = gid >> 11;
  const int od = odt * 16 + fr;
  const int k = kc * 32 + koct * 8;
  const int w = k / ESTR;
  const int hl = k - w * ESTR;
  const int h = hl >> 4, lW = hl & 15;
  const float* src = W + (size_t)(w * IN_H + h) * 8192 + od * 16 + lW;
  float4 a = *(const float4*)src;
  float4 b = *(const float4*)(src + 4);
  uint4 v;
  v.x = f2bf(a.x) | (f2bf(a.y) << 16);
  v.y = f2bf(a.z) | (f2bf(a.w) << 16);
  v.z = f2bf(b.x) | (f2bf(b.y) << 16);
  v.w = f2bf(b.z) | (f2bf(b.w) << 16);
  *(uint4*)(Btf + (size_t)gid * 8) = v;
}

// ---------------- pack_a: materialize windowed A-operand in fragment order.
// weF[gid*8..+7] for gid = pt*(K/32)*64 + kc*64 + l: lane l of (pt,kc) tile
// holds embB[row + w - 2][c..c+7], row = pt*16 + (l&15), k = kc*32+(l>>4)*8.
// Writes linear; the scattered 16-B reads happen ONCE here instead of inside
// sa_gemm's K-loop (r15/r16 failure: 64 lines per wave-load, L1-transaction
// bound ~30us/layer).
template <int K, int ESTR>
__global__ __launch_bounds__(256) void pack_a(
    const unsigned short* __restrict__ embB, unsigned short* __restrict__ weF) {
  int gid = blockIdx.x * 256 + threadIdx.x;
  const int l = gid & 63;
  const int kc = (gid >> 6) % (K / 32);
  const int pt = gid / (64 * (K / 32));
  const int fr = l & 15;
  const int k = kc * 32 + (l >> 4) * 8;
  const int w = k / ESTR;
  const int c = k - w * ESTR;
  const int row = pt * 16 + fr;
  const int s = (row & 255) + w - 2;
  uint4 v = {0, 0, 0, 0};
  if (s >= 0 && s < SEQ)
    v = *(const uint4*)(embB + (size_t)(row + w - 2) * ESTR + c);
  *(uint4*)(weF + (size_t)gid * 8) = v;
}

// ---------------- bias sum (parallel): grid(4) x 512thr
template <int INH>
__global__ __launch_bounds__(512) void bias_sum(
    const float* __restrict__ Bi, float* __restrict__ bias) {
  __shared__ float lds[4][128];
  const int odl = threadIdx.x & 127;
  const int part = threadIdx.x >> 7;
  const int od = blockIdx.x * 128 + odl;
  float s = 0.f;
  for (int i = part; i < INH; i += 4) s += Bi[(size_t)i * 512 + od];
  lds[part][odl] = s;
  __syncthreads();
  if (part == 0) bias[od] = lds[0][odl] + lds[1][odl] + lds[2][odl] + lds[3][odl];
}

// ---------------- sa_gemm v4: both operands pre-swizzled to fragment order
// -> every load is a fully-coalesced 1KB wave-load (16 lines, not 64).
// No LDS, no barriers. Block = 4 waves sharing the A tile (L1 reuse).
template <int K>
__global__ __launch_bounds__(256) void sa_gemm(
    const unsigned short* __restrict__ weF, const unsigned short* __restrict__ Btf,
    const float* __restrict__ bias, float* __restrict__ sA) {
  constexpr int KC32 = K / 32;
  const int pt = blockIdx.x;      // 16 positions
  const int og = blockIdx.y;      // 8 groups x 4 waves = 32 od-tiles
  const int t = threadIdx.x;
  const int wv = t >> 6, l = t & 63;
  const int odt = og * 4 + wv;
  const int od0 = odt * 16;
  const unsigned short* ap = weF + (size_t)pt * KC32 * 512 + l * 8;
  const unsigned short* bp = Btf + (size_t)odt * 512 + (l & 15) * 32 + (l >> 4) * 8;
  f32x4 acc = {0.f, 0.f, 0.f, 0.f};
#pragma unroll 4
  for (int kc = 0; kc < KC32; kc++) {
    bf16x8 af = *(const bf16x8*)(ap + (size_t)kc * 512);
    bf16x8 bf = *(const bf16x8*)(bp + (size_t)kc * 16384);
    acc = __builtin_amdgcn_mfma_f32_16x16x32_bf16(af, bf, acc, 0, 0, 0);
  }
  const int fr = l & 15;
  const float bs = bias[od0 + fr];
#pragma unroll
  for (int j = 0; j < 4; j++) {
    int r = (l >> 4) * 4 + j;
    sA[(size_t)(pt * 16 + r) * 512 + od0 + fr] = acc[j] + bs;
  }
}

// ---------------- einsum (r12 PT=64 version, half2 stores)
template <int INH, int IN_H, int ESTR>
__global__ __launch_bounds__(512) void einsum_kernel(
    const float* __restrict__ W, const float* __restrict__ Bi,
    const float* __restrict__ emb, __half* __restrict__ u, int pos0) {
  constexpr int PT = 64;
  const int i = blockIdx.x;
  const int pt = blockIdx.y;
  const int t = threadIdx.x;
  const int c = t & 255;
  const int ph = t >> 8;
  const int w = i / IN_H, h = i % IN_H;
  __shared__ float W_lds[16][512];
  __shared__ float we_lds[PT][16];
  const float* Wi = W + (size_t)i * 8192;
#pragma unroll
  for (int j = 0; j < 4; j++) {
    const float4 wv = *(const float4*)(Wi + (size_t)t * 16 + j * 4);
    W_lds[j * 4 + 0][t] = wv.x; W_lds[j * 4 + 1][t] = wv.y;
    W_lds[j * 4 + 2][t] = wv.z; W_lds[j * 4 + 3][t] = wv.w;
  }
#pragma unroll
  for (int j = 0; j < PT * 16 / 512; j++) {
    int idx = t + j * 512;
    int p = idx >> 4, l = idx & 15;
    int pos = pos0 + pt * PT + p;
    int s = pos & 255;
    int sr = s + w - 2;
    float val = 0.f;
    if (sr >= 0 && sr < SEQ) val = emb[(size_t)(pos + (w - 2)) * ESTR + h * 16 + l];
    we_lds[p][l] = val;
  }
  __syncthreads();
  float wr0[16], wr1[16];
#pragma unroll
  for (int l = 0; l < 16; l++) { wr0[l] = W_lds[l][2 * c]; wr1[l] = W_lds[l][2 * c + 1]; }
  const float b0 = Bi[(size_t)i * 512 + 2 * c];
  const float b1 = Bi[(size_t)i * 512 + 2 * c + 1];
  __half* ub = u + ((size_t)(pt * PT + ph * 32) * INH + i) * 512 + 2 * c;
#pragma unroll 4
  for (int p2 = 0; p2 < 32; p2++) {
    const int p = ph * 32 + p2;
    float a0 = b0, a1 = b1;
#pragma unroll
    for (int l = 0; l < 16; l++) {
      float e = we_lds[p][l];
      a0 = fmaf(wr0[l], e, a0);
      a1 = fmaf(wr1[l], e, a1);
    }
    *(__half2*)(ub + (size_t)p2 * INH * 512) = __floats2half2_rn(a0, a1);
  }
}

// ---------------- routing (r15 verbatim): pass A from precomputed sA;
// u_hat streamed 2x -> 6.2 TB/s combined delivery ceiling. DPP softmax.
template <int INH, bool MASK, bool FINAL>
__global__ __launch_bounds__(512) void route_kernel(
    const __half* __restrict__ u, const float* __restrict__ sA,
    const float* __restrict__ g, const float* __restrict__ be,
    const float* __restrict__ g_o, const float* __restrict__ b_o,
    float* __restrict__ outp, unsigned short* __restrict__ outb, int pos0) {
  constexpr int ROWS = INH / 8;
  const int w = threadIdx.x >> 6;
  const int l = threadIdx.x & 63;
  const int o = l >> 1;
  const int p = blockIdx.x;
  const int posg = pos0 + p;
  const int xaddr = ((l ^ 32) << 2);
  const __half* ug = u + (size_t)p * INH * 512 + (size_t)w * ROWS * 512 + l * 8;

  __shared__ float red_s[8][512];

#define UNPACK(q, f)                                            \
  {                                                             \
    float2 f0 = __half22float2(*(const __half2*)&(q).x);        \
    float2 f1 = __half22float2(*(const __half2*)&(q).y);        \
    float2 f2 = __half22float2(*(const __half2*)&(q).z);        \
    float2 f3 = __half22float2(*(const __half2*)&(q).w);        \
    f[0] = f0.x; f[1] = f0.y; f[2] = f1.x; f[3] = f1.y;         \
    f[4] = f2.x; f[5] = f2.y; f[6] = f3.x; f[7] = f3.y;         \
  }

  // ---- iter 1 from precomputed sA (2KB/position, L2-hot)
  float s8[8];
  {
    const float* sp = sA + (size_t)posg * 512 + l * 8;
    float4 a = *(const float4*)sp;
    float4 b = *(const float4*)(sp + 4);
    s8[0] = a.x; s8[1] = a.y; s8[2] = a.z; s8[3] = a.w;
    s8[4] = b.x; s8[5] = b.y; s8[6] = b.z; s8[7] = b.w;
  }
  const float c1 = MASK ? (o == 0 ? 0.f : (1.f / 31.f)) : (1.f / 32.f);
  float vd[8], vout[8];
  {
    float sn = 0.f;
#pragma unroll
    for (int k = 0; k < 8; k++) { s8[k] *= c1; sn += s8[k] * s8[k]; }
    sn = dpp_add<DPP_XOR1>(sn);
    float f = (sn / (1.f + sn)) * rsqrtf(sn + 1e-9f);
#pragma unroll
    for (int k = 0; k < 8; k++) vd[k] = s8[k] * f;  // vd = v1
  }

  // ---- passes B, C (iters 2, 3); pass C dots against v1+v2 (b telescopes)
#pragma unroll
  for (int iter = 0; iter < 2; iter++) {
    float sacc[8];
#pragma unroll
    for (int k = 0; k < 8; k++) sacc[k] = 0.f;
#pragma unroll 2
    for (int r = 0; r < ROWS; r++) {
      uint4 q = *(const uint4*)(ug + (size_t)r * 512);
      float u8[8];
      UNPACK(q, u8);
      float a = u8[0] * vd[0];
#pragma unroll
      for (int k = 1; k < 8; k++) a = fmaf(u8[k], vd[k], a);
      a = dpp_add<DPP_XOR1>(a);
      float e = (MASK && o == 0) ? 0.f : __expf(a);
      float ss = dpp_add<DPP_XOR1>(e);
      ss = dpp_add<DPP_XOR2>(ss);
      ss = dpp_add<DPP_ROR4>(ss);
      ss = dpp_add<DPP_ROR8>(ss);
      ss += swz_xor16(ss);
      ss += bperm(xaddr, ss);
      float c = __fdividef(e + e, ss);
#pragma unroll
      for (int k = 0; k < 8; k++) sacc[k] = fmaf(c, u8[k], sacc[k]);
    }
    __syncthreads();
    *(float4*)&red_s[w][l * 8]     = make_float4(sacc[0], sacc[1], sacc[2], sacc[3]);
    *(float4*)&red_s[w][l * 8 + 4] = make_float4(sacc[4], sacc[5], sacc[6], sacc[7]);
    __syncthreads();
#pragma unroll
    for (int k = 0; k < 8; k++) sacc[k] = 0.f;
#pragma unroll
    for (int w2 = 0; w2 < 8; w2++) {
      float4 a = *(const float4*)&red_s[w2][l * 8];
      float4 b = *(const float4*)&red_s[w2][l * 8 + 4];
      sacc[0] += a.x; sacc[1] += a.y; sacc[2] += a.z; sacc[3] += a.w;
      sacc[4] += b.x; sacc[5] += b.y; sacc[6] += b.z; sacc[7] += b.w;
    }
    float sn = 0.f;
#pragma unroll
    for (int k = 0; k < 8; k++) sn += sacc[k] * sacc[k];
    sn = dpp_add<DPP_XOR1>(sn);
    float f = (sn / (1.f + sn)) * rsqrtf(sn + 1e-9f);
#pragma unroll
    for (int k = 0; k < 8; k++) {
      vout[k] = sacc[k] * f;
      vd[k] += vout[k];
    }
  }

  // ---- epilogue: LN over 512
  float s1 = 0.f, s2 = 0.f;
#pragma unroll
  for (int k = 0; k < 8; k++) { s1 += vout[k]; s2 += vout[k] * vout[k]; }
  for (int m = 1; m < 64; m <<= 1) { s1 += __shfl_xor(s1, m); s2 += __shfl_xor(s2, m); }
  float mean = s1 * (1.f / 512.f);
  float var = s2 * (1.f / 512.f) - mean * mean;
  float rstd = rsqrtf(var + 1e-3f);
  const float4 g0 = *(const float4*)(g + 8 * l);
  const float4 g1 = *(const float4*)(g + 8 * l + 4);
  const float4 be0 = *(const float4*)(be + 8 * l);
  const float4 be1 = *(const float4*)(be + 8 * l + 4);
  float nv[8];
  nv[0] = g0.x * (vout[0] - mean) * rstd + be0.x;
  nv[1] = g0.y * (vout[1] - mean) * rstd + be0.y;
  nv[2] = g0.z * (vout[2] - mean) * rstd + be0.z;
  nv[3] = g0.w * (vout[3] - mean) * rstd + be0.w;
  nv[4] = g1.x * (vout[4] - mean) * rstd + be1.x;
  nv[5] = g1.y * (vout[5] - mean) * rstd + be1.y;
  nv[6] = g1.z * (vout[6] - mean) * rstd + be1.z;
  nv[7] = g1.w * (vout[7] - mean) * rstd + be1.w;

  if (!FINAL) {
    if (w == 0) {
      float4 w0 = {nv[0], nv[1], nv[2], nv[3]};
      float4 w1 = {nv[4], nv[5], nv[6], nv[7]};
      float* op = outp + (size_t)posg * 512 + 8 * l;
      *(float4*)op = w0; *(float4*)(op + 4) = w1;
      uint4 bb;
      bb.x = f2bf(nv[0]) | (f2bf(nv[1]) << 16);
      bb.y = f2bf(nv[2]) | (f2bf(nv[3]) << 16);
      bb.z = f2bf(nv[4]) | (f2bf(nv[5]) << 16);
      bb.w = f2bf(nv[6]) | (f2bf(nv[7]) << 16);
      *(uint4*)(outb + (size_t)posg * 512 + 8 * l) = bb;
    }
  } else {
    float l2 = 0.f;
#pragma unroll
    for (int k = 0; k < 8; k++) l2 += nv[k] * nv[k];
    l2 = dpp_add<DPP_XOR1>(l2);
    float len = sqrtf(l2 + 1e-9f);
    float a1 = len, a2 = len * len;
    for (int m = 1; m < 64; m <<= 1) { a1 += __shfl_xor(a1, m); a2 += __shfl_xor(a2, m); }
    float mm = a1 * (1.f / 64.f);
    float vv = a2 * (1.f / 64.f) - mm * mm;
    if (w == 0 && (l & 1) == 0)
      outp[(size_t)posg * 32 + o] = g_o[o] * (len - mm) * rsqrtf(vv + 1e-3f) + b_o[o];
  }
#undef UNPACK
}

extern "C" void kernel_launch(void* const* d_in, const int* in_sizes, int n_in,
                              void* d_out, int out_size, void* d_ws, size_t ws_size,
                              hipStream_t stream) {
  const float* x    = (const float*)d_in[0];
  const float* W0   = (const float*)d_in[1];
  const float* B0   = (const float*)d_in[2];
  const float* W1   = (const float*)d_in[3];
  const float* B1   = (const float*)d_in[4];
  const float* g_i  = (const float*)d_in[5];
  const float* b_i  = (const float*)d_in[6];
  const float* g_m0 = (const float*)d_in[7];
  const float* b_m0 = (const float*)d_in[8];
  const float* g_m1 = (const float*)d_in[9];
  const float* b_m1 = (const float*)d_in[10];
  const float* g_o  = (const float*)d_in[11];
  const float* b_o  = (const float*)d_in[12];
  float* out = (float*)d_out;

  char* ws = (char*)d_ws;
  float* emb0            = (float*)(ws);                      // 1 MB
  float* emb1            = (float*)(ws + 1048576);            // 2 MB
  unsigned short* emb0b  = (unsigned short*)(ws + 3145728);   // 0.5 MB
  unsigned short* emb1b  = (unsigned short*)(ws + 3670016);   // 1 MB
  float* sA0             = (float*)(ws + 4718592);            // 2 MB
  float* sA1             = (float*)(ws + 6815744);            // 2 MB
  unsigned short* Btf0   = (unsigned short*)(ws + 8912896);   // 1.25 MB
  unsigned short* Btf1   = (unsigned short*)(ws + 10223616);  // 2.5 MB
  unsigned short* weF0   = (unsigned short*)(ws + 12845056);  // 2.5 MB
  unsigned short* weF1   = (unsigned short*)(ws + 15466496);  // 5.25 MB
  float* bias0           = (float*)(ws + 20709376);           // 2 KB
  float* bias1           = (float*)(ws + 20711424);           // 2 KB
  __half* ubuf           = (__half*)(ws + 20971520);

  size_t avail = ws_size > (size_t)20971520 ? ws_size - 20971520 : 0;
  int chunk = 1024;
  while (chunk > 128 && (size_t)chunk * 163840 > avail) chunk >>= 1;

  prep_kernel<<<NPOS, 256, 0, stream>>>(x, g_i, b_i, emb0, emb0b);
  conv_btf<1280, 256, 16><<<(512 * 160 + 255) / 256, 256, 0, stream>>>(W0, Btf0);
  conv_btf<2560, 512, 32><<<(512 * 320 + 255) / 256, 256, 0, stream>>>(W1, Btf1);
  bias_sum<80><<<4, 512, 0, stream>>>(B0, bias0);
  bias_sum<160><<<4, 512, 0, stream>>>(B1, bias1);
  pack_a<1280, 256><<<640, 256, 0, stream>>>(emb0b, weF0);
  sa_gemm<1280><<<dim3(64, 8), 256, 0, stream>>>(weF0, Btf0, bias0, sA0);

  for (int p0 = 0; p0 < NPOS; p0 += chunk) {
    int cp = (NPOS - p0 < chunk) ? (NPOS - p0) : chunk;
    einsum_kernel<80, 16, 256><<<dim3(80, cp / 64), 512, 0, stream>>>(W0, B0, emb0, ubuf, p0);
    route_kernel<80, false, false><<<cp, 512, 0, stream>>>(ubuf, sA0, g_m0, b_m0, nullptr, nullptr, emb1, emb1b, p0);
  }

  pack_a<2560, 512><<<1280, 256, 0, stream>>>(emb1b, weF1);
  sa_gemm<2560><<<dim3(64, 8), 256, 0, stream>>>(weF1, Btf1, bias1, sA1);

  for (int p0 = 0; p0 < NPOS; p0 += chunk) {
    int cp = (NPOS - p0 < chunk) ? (NPOS - p0) : chunk;
    einsum_kernel<160, 32, 512><<<dim3(160, cp / 64), 512, 0, stream>>>(W1, B1, emb1, ubuf, p0);
    route_kernel<160, true, true><<<cp, 512, 0, stream>>>(ubuf, sA1, g_m1, b_m1, g_o, b_o, out, nullptr, p0);
  }
}

// Round 18
// 200.323 us; speedup vs baseline: 1.2052x; 1.0788x over previous
//
#include <hip/hip_runtime.h>
#include <hip/hip_fp16.h>

#define SEQ 256
#define NPOS 1024

typedef __attribute__((ext_vector_type(8))) short bf16x8;
typedef __attribute__((ext_vector_type(4))) float f32x4;

__device__ __forceinline__ unsigned f2bf(float x) {
  unsigned int u = __float_as_uint(x);
  return (u + 0x7FFFu + ((u >> 16) & 1u)) >> 16;
}

// DPP cross-lane add helpers (VALU pipe)
template <int CTRL>
__device__ __forceinline__ float dpp_add(float x) {
  return x + __int_as_float(__builtin_amdgcn_update_dpp(
                 0, __float_as_int(x), CTRL, 0xF, 0xF, true));
}
#define DPP_XOR1 0xB1
#define DPP_XOR2 0x4E
#define DPP_ROR4 0x124
#define DPP_ROR8 0x128
__device__ __forceinline__ float swz_xor16(float x) {
  return __int_as_float(__builtin_amdgcn_ds_swizzle(__float_as_int(x), 0x401F));
}
__device__ __forceinline__ float bperm(int addr, float x) {
  return __int_as_float(__builtin_amdgcn_ds_bpermute(addr, __float_as_int(x)));
}

// ---------------- prep: squash + LN -> emb0 (fp32)
__global__ __launch_bounds__(256) void prep_kernel(
    const float* __restrict__ x, const float* __restrict__ g,
    const float* __restrict__ be, float* __restrict__ emb0) {
  const int pos = blockIdx.x;
  const int t = threadIdx.x;
  float v = x[(size_t)pos * 256 + t];
  float sn = v * v;
  sn += __shfl_xor(sn, 1); sn += __shfl_xor(sn, 2);
  sn += __shfl_xor(sn, 4); sn += __shfl_xor(sn, 8);
  float e = v * (sn / (1.f + sn)) * rsqrtf(sn + 1e-9f);
  __shared__ float red[2][4];
  float s1 = e, s2 = e * e;
  for (int m = 1; m < 64; m <<= 1) { s1 += __shfl_xor(s1, m); s2 += __shfl_xor(s2, m); }
  if ((t & 63) == 0) { red[0][t >> 6] = s1; red[1][t >> 6] = s2; }
  __syncthreads();
  float tot = 0.f, tot2 = 0.f;
#pragma unroll
  for (int i = 0; i < 4; i++) { tot += red[0][i]; tot2 += red[1][i]; }
  float mean = tot * (1.f / 256.f);
  float var = tot2 * (1.f / 256.f) - mean * mean;
  emb0[(size_t)pos * 256 + t] = g[t] * (e - mean) * rsqrtf(var + 1e-3f) + be[t];
}

// ---------------- convbias1: fused Btf1 builder (fragment order) + bias1 sum
// blocks 0..639: Btf; blocks 640..641: bias
__global__ __launch_bounds__(256) void convbias1(
    const float* __restrict__ W1, const float* __restrict__ B1,
    unsigned short* __restrict__ Btf, float* __restrict__ bias) {
  const int blk = blockIdx.x;
  if (blk < 640) {
    int gid = blk * 256 + threadIdx.x;  // < 512*320
    const int koct = gid & 3;
    const int fr = (gid >> 2) & 15;
    const int odt = (gid >> 6) & 31;
    const int kc = gid >> 11;
    const int od = odt * 16 + fr;
    const int k = kc * 32 + koct * 8;
    const int w = k >> 9;            // ESTR=512
    const int hl = k & 511;
    const int h = hl >> 4, lW = hl & 15;
    const float* src = W1 + (size_t)(w * 32 + h) * 8192 + od * 16 + lW;
    float4 a = *(const float4*)src;
    float4 b = *(const float4*)(src + 4);
    uint4 v;
    v.x = f2bf(a.x) | (f2bf(a.y) << 16);
    v.y = f2bf(a.z) | (f2bf(a.w) << 16);
    v.z = f2bf(b.x) | (f2bf(b.y) << 16);
    v.w = f2bf(b.z) | (f2bf(b.w) << 16);
    *(uint4*)(Btf + (size_t)gid * 8) = v;
  } else {
    const int od = (blk - 640) * 256 + threadIdx.x;
    float s = 0.f;
    for (int i = 0; i < 160; i++) s += B1[(size_t)i * 512 + od];
    bias[od] = s;
  }
}

// ---------------- pack_a1: windowed A-operand in fragment order (layer 1)
__global__ __launch_bounds__(256) void pack_a1(
    const unsigned short* __restrict__ embB, unsigned short* __restrict__ weF) {
  int gid = blockIdx.x * 256 + threadIdx.x;  // 64pt * 80kc * 64l = 327680
  const int l = gid & 63;
  const int kc = (gid >> 6) % 80;
  const int pt = gid / (64 * 80);
  const int fr = l & 15;
  const int k = kc * 32 + (l >> 4) * 8;
  const int w = k >> 9;
  const int c = k & 511;
  const int row = pt * 16 + fr;
  const int s = (row & 255) + w - 2;
  uint4 v = {0, 0, 0, 0};
  if (s >= 0 && s < SEQ)
    v = *(const uint4*)(embB + (size_t)(row + w - 2) * 512 + c);
  *(uint4*)(weF + (size_t)gid * 8) = v;
}

// ---------------- sa_gemm (layer 1, K=2560): fragment-order operands,
// fully-coalesced 1KB wave-loads, no LDS, no barriers (r17-verified).
__global__ __launch_bounds__(256) void sa_gemm1(
    const unsigned short* __restrict__ weF, const unsigned short* __restrict__ Btf,
    const float* __restrict__ bias, float* __restrict__ sA) {
  constexpr int KC32 = 80;
  const int pt = blockIdx.x;
  const int og = blockIdx.y;
  const int t = threadIdx.x;
  const int wv = t >> 6, l = t & 63;
  const int odt = og * 4 + wv;
  const int od0 = odt * 16;
  const unsigned short* ap = weF + (size_t)pt * KC32 * 512 + l * 8;
  const unsigned short* bp = Btf + (size_t)odt * 512 + (l & 15) * 32 + (l >> 4) * 8;
  f32x4 acc = {0.f, 0.f, 0.f, 0.f};
#pragma unroll 4
  for (int kc = 0; kc < KC32; kc++) {
    bf16x8 af = *(const bf16x8*)(ap + (size_t)kc * 512);
    bf16x8 bf = *(const bf16x8*)(bp + (size_t)kc * 16384);
    acc = __builtin_amdgcn_mfma_f32_16x16x32_bf16(af, bf, acc, 0, 0, 0);
  }
  const int fr = l & 15;
  const float bs = bias[od0 + fr];
#pragma unroll
  for (int j = 0; j < 4; j++) {
    int r = (l >> 4) * 4 + j;
    sA[(size_t)(pt * 16 + r) * 512 + od0 + fr] = acc[j] + bs;
  }
}

// ---------------- einsum (r12 PT=64 version, half2 stores)
template <int INH, int IN_H, int ESTR>
__global__ __launch_bounds__(512) void einsum_kernel(
    const float* __restrict__ W, const float* __restrict__ Bi,
    const float* __restrict__ emb, __half* __restrict__ u, int pos0) {
  constexpr int PT = 64;
  const int i = blockIdx.x;
  const int pt = blockIdx.y;
  const int t = threadIdx.x;
  const int c = t & 255;
  const int ph = t >> 8;
  const int w = i / IN_H, h = i % IN_H;
  __shared__ float W_lds[16][512];
  __shared__ float we_lds[PT][16];
  const float* Wi = W + (size_t)i * 8192;
#pragma unroll
  for (int j = 0; j < 4; j++) {
    const float4 wv = *(const float4*)(Wi + (size_t)t * 16 + j * 4);
    W_lds[j * 4 + 0][t] = wv.x; W_lds[j * 4 + 1][t] = wv.y;
    W_lds[j * 4 + 2][t] = wv.z; W_lds[j * 4 + 3][t] = wv.w;
  }
#pragma unroll
  for (int j = 0; j < PT * 16 / 512; j++) {
    int idx = t + j * 512;
    int p = idx >> 4, l = idx & 15;
    int pos = pos0 + pt * PT + p;
    int s = pos & 255;
    int sr = s + w - 2;
    float val = 0.f;
    if (sr >= 0 && sr < SEQ) val = emb[(size_t)(pos + (w - 2)) * ESTR + h * 16 + l];
    we_lds[p][l] = val;
  }
  __syncthreads();
  float wr0[16], wr1[16];
#pragma unroll
  for (int l = 0; l < 16; l++) { wr0[l] = W_lds[l][2 * c]; wr1[l] = W_lds[l][2 * c + 1]; }
  const float b0 = Bi[(size_t)i * 512 + 2 * c];
  const float b1 = Bi[(size_t)i * 512 + 2 * c + 1];
  __half* ub = u + ((size_t)(pt * PT + ph * 32) * INH + i) * 512 + 2 * c;
#pragma unroll 4
  for (int p2 = 0; p2 < 32; p2++) {
    const int p = ph * 32 + p2;
    float a0 = b0, a1 = b1;
#pragma unroll
    for (int l = 0; l < 16; l++) {
      float e = we_lds[p][l];
      a0 = fmaf(wr0[l], e, a0);
      a1 = fmaf(wr1[l], e, a1);
    }
    *(__half2*)(ub + (size_t)p2 * INH * 512) = __floats2half2_rn(a0, a1);
  }
}

// ---------------- routing: USESA=false -> r12 3-pass (pass A streams u_hat);
// USESA=true -> pass A from precomputed sA (u_hat streamed 2x). DPP softmax.
// Both at the ~6.2-6.3 TB/s combined delivery ceiling (r12/r15 measured).
template <int INH, bool USESA, bool MASK, bool FINAL>
__global__ __launch_bounds__(512) void route_kernel(
    const __half* __restrict__ u, const float* __restrict__ sA,
    const float* __restrict__ g, const float* __restrict__ be,
    const float* __restrict__ g_o, const float* __restrict__ b_o,
    float* __restrict__ outp, unsigned short* __restrict__ outb, int pos0) {
  constexpr int ROWS = INH / 8;
  const int w = threadIdx.x >> 6;
  const int l = threadIdx.x & 63;
  const int o = l >> 1;
  const int p = blockIdx.x;
  const int posg = pos0 + p;
  const int xaddr = ((l ^ 32) << 2);
  const __half* ug = u + (size_t)p * INH * 512 + (size_t)w * ROWS * 512 + l * 8;

  __shared__ float red_s[8][512];

#define UNPACK(q, f)                                            \
  {                                                             \
    float2 f0 = __half22float2(*(const __half2*)&(q).x);        \
    float2 f1 = __half22float2(*(const __half2*)&(q).y);        \
    float2 f2 = __half22float2(*(const __half2*)&(q).z);        \
    float2 f3 = __half22float2(*(const __half2*)&(q).w);        \
    f[0] = f0.x; f[1] = f0.y; f[2] = f1.x; f[3] = f1.y;         \
    f[4] = f2.x; f[5] = f2.y; f[6] = f3.x; f[7] = f3.y;         \
  }

  // ---- iter 1: from sA (USESA) or streamed row-sum (r12 path)
  float s8[8];
  if (USESA) {
    const float* sp = sA + (size_t)posg * 512 + l * 8;
    float4 a = *(const float4*)sp;
    float4 b = *(const float4*)(sp + 4);
    s8[0] = a.x; s8[1] = a.y; s8[2] = a.z; s8[3] = a.w;
    s8[4] = b.x; s8[5] = b.y; s8[6] = b.z; s8[7] = b.w;
  } else {
#pragma unroll
    for (int k = 0; k < 8; k++) s8[k] = 0.f;
#pragma unroll 4
    for (int r = 0; r < ROWS; r++) {
      uint4 q = *(const uint4*)(ug + (size_t)r * 512);
      float u8[8];
      UNPACK(q, u8);
#pragma unroll
      for (int k = 0; k < 8; k++) s8[k] += u8[k];
    }
    *(float4*)&red_s[w][l * 8]     = make_float4(s8[0], s8[1], s8[2], s8[3]);
    *(float4*)&red_s[w][l * 8 + 4] = make_float4(s8[4], s8[5], s8[6], s8[7]);
    __syncthreads();
#pragma unroll
    for (int k = 0; k < 8; k++) s8[k] = 0.f;
#pragma unroll
    for (int w2 = 0; w2 < 8; w2++) {
      float4 a = *(const float4*)&red_s[w2][l * 8];
      float4 b = *(const float4*)&red_s[w2][l * 8 + 4];
      s8[0] += a.x; s8[1] += a.y; s8[2] += a.z; s8[3] += a.w;
      s8[4] += b.x; s8[5] += b.y; s8[6] += b.z; s8[7] += b.w;
    }
  }
  const float c1 = MASK ? (o == 0 ? 0.f : (1.f / 31.f)) : (1.f / 32.f);
  float vd[8], vout[8];
  {
    float sn = 0.f;
#pragma unroll
    for (int k = 0; k < 8; k++) { s8[k] *= c1; sn += s8[k] * s8[k]; }
    sn = dpp_add<DPP_XOR1>(sn);
    float f = (sn / (1.f + sn)) * rsqrtf(sn + 1e-9f);
#pragma unroll
    for (int k = 0; k < 8; k++) vd[k] = s8[k] * f;  // vd = v1
  }

  // ---- passes B, C (iters 2, 3); pass C dots against v1+v2 (b telescopes)
#pragma unroll
  for (int iter = 0; iter < 2; iter++) {
    float sacc[8];
#pragma unroll
    for (int k = 0; k < 8; k++) sacc[k] = 0.f;
#pragma unroll 2
    for (int r = 0; r < ROWS; r++) {
      uint4 q = *(const uint4*)(ug + (size_t)r * 512);
      float u8[8];
      UNPACK(q, u8);
      float a = u8[0] * vd[0];
#pragma unroll
      for (int k = 1; k < 8; k++) a = fmaf(u8[k], vd[k], a);
      a = dpp_add<DPP_XOR1>(a);
      float e = (MASK && o == 0) ? 0.f : __expf(a);
      float ss = dpp_add<DPP_XOR1>(e);
      ss = dpp_add<DPP_XOR2>(ss);
      ss = dpp_add<DPP_ROR4>(ss);
      ss = dpp_add<DPP_ROR8>(ss);
      ss += swz_xor16(ss);
      ss += bperm(xaddr, ss);
      float c = __fdividef(e + e, ss);
#pragma unroll
      for (int k = 0; k < 8; k++) sacc[k] = fmaf(c, u8[k], sacc[k]);
    }
    __syncthreads();
    *(float4*)&red_s[w][l * 8]     = make_float4(sacc[0], sacc[1], sacc[2], sacc[3]);
    *(float4*)&red_s[w][l * 8 + 4] = make_float4(sacc[4], sacc[5], sacc[6], sacc[7]);
    __syncthreads();
#pragma unroll
    for (int k = 0; k < 8; k++) sacc[k] = 0.f;
#pragma unroll
    for (int w2 = 0; w2 < 8; w2++) {
      float4 a = *(const float4*)&red_s[w2][l * 8];
      float4 b = *(const float4*)&red_s[w2][l * 8 + 4];
      sacc[0] += a.x; sacc[1] += a.y; sacc[2] += a.z; sacc[3] += a.w;
      sacc[4] += b.x; sacc[5] += b.y; sacc[6] += b.z; sacc[7] += b.w;
    }
    float sn = 0.f;
#pragma unroll
    for (int k = 0; k < 8; k++) sn += sacc[k] * sacc[k];
    sn = dpp_add<DPP_XOR1>(sn);
    float f = (sn / (1.f + sn)) * rsqrtf(sn + 1e-9f);
#pragma unroll
    for (int k = 0; k < 8; k++) {
      vout[k] = sacc[k] * f;
      vd[k] += vout[k];
    }
  }

  // ---- epilogue: LN over 512
  float s1 = 0.f, s2 = 0.f;
#pragma unroll
  for (int k = 0; k < 8; k++) { s1 += vout[k]; s2 += vout[k] * vout[k]; }
  for (int m = 1; m < 64; m <<= 1) { s1 += __shfl_xor(s1, m); s2 += __shfl_xor(s2, m); }
  float mean = s1 * (1.f / 512.f);
  float var = s2 * (1.f / 512.f) - mean * mean;
  float rstd = rsqrtf(var + 1e-3f);
  const float4 g0 = *(const float4*)(g + 8 * l);
  const float4 g1 = *(const float4*)(g + 8 * l + 4);
  const float4 be0 = *(const float4*)(be + 8 * l);
  const float4 be1 = *(const float4*)(be + 8 * l + 4);
  float nv[8];
  nv[0] = g0.x * (vout[0] - mean) * rstd + be0.x;
  nv[1] = g0.y * (vout[1] - mean) * rstd + be0.y;
  nv[2] = g0.z * (vout[2] - mean) * rstd + be0.z;
  nv[3] = g0.w * (vout[3] - mean) * rstd + be0.w;
  nv[4] = g1.x * (vout[4] - mean) * rstd + be1.x;
  nv[5] = g1.y * (vout[5] - mean) * rstd + be1.y;
  nv[6] = g1.z * (vout[6] - mean) * rstd + be1.z;
  nv[7] = g1.w * (vout[7] - mean) * rstd + be1.w;

  if (!FINAL) {
    if (w == 0) {
      float4 w0 = {nv[0], nv[1], nv[2], nv[3]};
      float4 w1 = {nv[4], nv[5], nv[6], nv[7]};
      float* op = outp + (size_t)posg * 512 + 8 * l;
      *(float4*)op = w0; *(float4*)(op + 4) = w1;
      if (outb) {
        uint4 bb;
        bb.x = f2bf(nv[0]) | (f2bf(nv[1]) << 16);
        bb.y = f2bf(nv[2]) | (f2bf(nv[3]) << 16);
        bb.z = f2bf(nv[4]) | (f2bf(nv[5]) << 16);
        bb.w = f2bf(nv[6]) | (f2bf(nv[7]) << 16);
        *(uint4*)(outb + (size_t)posg * 512 + 8 * l) = bb;
      }
    }
  } else {
    float l2 = 0.f;
#pragma unroll
    for (int k = 0; k < 8; k++) l2 += nv[k] * nv[k];
    l2 = dpp_add<DPP_XOR1>(l2);
    float len = sqrtf(l2 + 1e-9f);
    float a1 = len, a2 = len * len;
    for (int m = 1; m < 64; m <<= 1) { a1 += __shfl_xor(a1, m); a2 += __shfl_xor(a2, m); }
    float mm = a1 * (1.f / 64.f);
    float vv = a2 * (1.f / 64.f) - mm * mm;
    if (w == 0 && (l & 1) == 0)
      outp[(size_t)posg * 32 + o] = g_o[o] * (len - mm) * rsqrtf(vv + 1e-3f) + b_o[o];
  }
#undef UNPACK
}

extern "C" void kernel_launch(void* const* d_in, const int* in_sizes, int n_in,
                              void* d_out, int out_size, void* d_ws, size_t ws_size,
                              hipStream_t stream) {
  const float* x    = (const float*)d_in[0];
  const float* W0   = (const float*)d_in[1];
  const float* B0   = (const float*)d_in[2];
  const float* W1   = (const float*)d_in[3];
  const float* B1   = (const float*)d_in[4];
  const float* g_i  = (const float*)d_in[5];
  const float* b_i  = (const float*)d_in[6];
  const float* g_m0 = (const float*)d_in[7];
  const float* b_m0 = (const float*)d_in[8];
  const float* g_m1 = (const float*)d_in[9];
  const float* b_m1 = (const float*)d_in[10];
  const float* g_o  = (const float*)d_in[11];
  const float* b_o  = (const float*)d_in[12];
  float* out = (float*)d_out;

  char* ws = (char*)d_ws;
  float* emb0            = (float*)(ws);                      // 1 MB
  float* emb1            = (float*)(ws + 1048576);            // 2 MB
  unsigned short* emb1b  = (unsigned short*)(ws + 3145728);   // 1 MB
  float* sA1             = (float*)(ws + 4194304);            // 2 MB
  unsigned short* Btf1   = (unsigned short*)(ws + 6291456);   // 2.5 MB
  unsigned short* weF1   = (unsigned short*)(ws + 8912896);   // 5 MB
  float* bias1           = (float*)(ws + 14155776);           // 2 KB
  __half* ubuf           = (__half*)(ws + 14680064);

  size_t avail = ws_size > (size_t)14680064 ? ws_size - 14680064 : 0;
  int chunk = 1024;
  while (chunk > 128 && (size_t)chunk * 163840 > avail) chunk >>= 1;

  prep_kernel<<<NPOS, 256, 0, stream>>>(x, g_i, b_i, emb0);
  convbias1<<<642, 256, 0, stream>>>(W1, B1, Btf1, bias1);

  for (int p0 = 0; p0 < NPOS; p0 += chunk) {
    int cp = (NPOS - p0 < chunk) ? (NPOS - p0) : chunk;
    einsum_kernel<80, 16, 256><<<dim3(80, cp / 64), 512, 0, stream>>>(W0, B0, emb0, ubuf, p0);
    route_kernel<80, false, false, false><<<cp, 512, 0, stream>>>(
        ubuf, nullptr, g_m0, b_m0, nullptr, nullptr, emb1, emb1b, p0);
  }

  pack_a1<<<1280, 256, 0, stream>>>(emb1b, weF1);
  sa_gemm1<<<dim3(64, 8), 256, 0, stream>>>(weF1, Btf1, bias1, sA1);

  for (int p0 = 0; p0 < NPOS; p0 += chunk) {
    int cp = (NPOS - p0 < chunk) ? (NPOS - p0) : chunk;
    einsum_kernel<160, 32, 512><<<dim3(160, cp / 64), 512, 0, stream>>>(W1, B1, emb1, ubuf, p0);
    route_kernel<160, true, true, true><<<cp, 512, 0, stream>>>(
        ubuf, sA1, g_m1, b_m1, g_o, b_o, out, nullptr, p0);
  }
}

// Round 19
// 196.004 us; speedup vs baseline: 1.2317x; 1.0220x over previous
//
#include <hip/hip_runtime.h>
#include <hip/hip_fp16.h>

#define SEQ 256
#define NPOS 1024

// DPP cross-lane add helpers (VALU pipe, ~2-4cy vs ~30cy DS shuffles)
template <int CTRL>
__device__ __forceinline__ float dpp_add(float x) {
  return x + __int_as_float(__builtin_amdgcn_update_dpp(
                 0, __float_as_int(x), CTRL, 0xF, 0xF, true));
}
#define DPP_XOR1 0xB1  // quad_perm [1,0,3,2]
#define DPP_XOR2 0x4E  // quad_perm [2,3,0,1]
#define DPP_ROR4 0x124 // row_ror:4
#define DPP_ROR8 0x128 // row_ror:8
__device__ __forceinline__ float swz_xor16(float x) {  // lane^16 within 32
  return __int_as_float(__builtin_amdgcn_ds_swizzle(__float_as_int(x), 0x401F));
}
__device__ __forceinline__ float bperm(int addr, float x) {  // pull lane addr>>2
  return __int_as_float(__builtin_amdgcn_ds_bpermute(addr, __float_as_int(x)));
}

// ---------------- prep: squash(x) + layernorm(g_i,b_i) -> emb0 [1024][256]
__global__ __launch_bounds__(256) void prep_kernel(
    const float* __restrict__ x, const float* __restrict__ g,
    const float* __restrict__ be, float* __restrict__ emb0) {
  const int pos = blockIdx.x;
  const int t = threadIdx.x;  // 256
  float v = x[(size_t)pos * 256 + t];
  float sn = v * v;
  sn += __shfl_xor(sn, 1); sn += __shfl_xor(sn, 2);
  sn += __shfl_xor(sn, 4); sn += __shfl_xor(sn, 8);
  float e = v * (sn / (1.f + sn)) * rsqrtf(sn + 1e-9f);
  __shared__ float red[2][4];
  float s1 = e, s2 = e * e;
  for (int m = 1; m < 64; m <<= 1) { s1 += __shfl_xor(s1, m); s2 += __shfl_xor(s2, m); }
  if ((t & 63) == 0) { red[0][t >> 6] = s1; red[1][t >> 6] = s2; }
  __syncthreads();
  float tot = 0.f, tot2 = 0.f;
#pragma unroll
  for (int i = 0; i < 4; i++) { tot += red[0][i]; tot2 += red[1][i]; }
  float mean = tot * (1.f / 256.f);
  float var = tot2 * (1.f / 256.f) - mean * mean;
  emb0[(size_t)pos * 256 + t] = g[t] * (e - mean) * rsqrtf(var + 1e-3f) + be[t];
}

// ---------------- einsum: u_hat[p,i,o,d] = sum_l W[i,o,d,l]*we[p,i,l] + B[i,o,d]
// block: (i, pos-subtile of 64); 512 threads. Each thread computes TWO
// adjacent od elements and stores one half2 dword (vectorized stores).
template <int INH, int IN_H, int ESTR>
__global__ __launch_bounds__(512) void einsum_kernel(
    const float* __restrict__ W, const float* __restrict__ Bi,
    const float* __restrict__ emb, __half* __restrict__ u, int pos0) {
  constexpr int PT = 64;
  const int i = blockIdx.x;
  const int pt = blockIdx.y;
  const int t = threadIdx.x;  // 512
  const int c = t & 255;      // od pair index: od = 2c, 2c+1
  const int ph = t >> 8;      // position half: 0 -> p 0..31, 1 -> p 32..63
  const int w = i / IN_H, h = i % IN_H;
  __shared__ float W_lds[16][512];   // [l][od]
  __shared__ float we_lds[PT][16];
  const float* Wi = W + (size_t)i * 8192;
#pragma unroll
  for (int j = 0; j < 4; j++) {
    const float4 wv = *(const float4*)(Wi + (size_t)t * 16 + j * 4);
    W_lds[j * 4 + 0][t] = wv.x; W_lds[j * 4 + 1][t] = wv.y;
    W_lds[j * 4 + 2][t] = wv.z; W_lds[j * 4 + 3][t] = wv.w;
  }
#pragma unroll
  for (int j = 0; j < PT * 16 / 512; j++) {
    int idx = t + j * 512;
    int p = idx >> 4, l = idx & 15;
    int pos = pos0 + pt * PT + p;
    int s = pos & 255;
    int sr = s + w - 2;
    float val = 0.f;
    if (sr >= 0 && sr < SEQ) val = emb[(size_t)(pos + (w - 2)) * ESTR + h * 16 + l];
    we_lds[p][l] = val;
  }
  __syncthreads();
  float wr0[16], wr1[16];
#pragma unroll
  for (int l = 0; l < 16; l++) { wr0[l] = W_lds[l][2 * c]; wr1[l] = W_lds[l][2 * c + 1]; }
  const float b0 = Bi[(size_t)i * 512 + 2 * c];
  const float b1 = Bi[(size_t)i * 512 + 2 * c + 1];
  __half* ub = u + ((size_t)(pt * PT + ph * 32) * INH + i) * 512 + 2 * c;
#pragma unroll 4
  for (int p2 = 0; p2 < 32; p2++) {
    const int p = ph * 32 + p2;
    float a0 = b0, a1 = b1;
#pragma unroll
    for (int l = 0; l < 16; l++) {
      float e = we_lds[p][l];
      a0 = fmaf(wr0[l], e, a0);
      a1 = fmaf(wr1[l], e, a1);
    }
    *(__half2*)(ub + (size_t)p2 * INH * 512) = __floats2half2_rn(a0, a1);
  }
}

// ---------------- routing: one block per position, 8 waves; u_hat STREAMED
// from global 3x. At the 6.2-6.3 TB/s combined (HBM+L3) delivery ceiling
// (measured r8/r11/r12/r15: bytes/time constant across compute variants).
// DPP-based softmax; per-row DS ops only ds_swizzle xor16 + ds_bpermute.
// VGPR stays 32 (<=64 class: 32 waves/CU; r9/r10 mapped the cliff at 64).
// lane l owns (o=l>>1, d=(l&1)*8..+8) of the 512-element s/v vectors.
template <int INH, bool MASK, bool FINAL>
__global__ __launch_bounds__(512) void route_kernel(
    const __half* __restrict__ u, const float* __restrict__ g,
    const float* __restrict__ be, const float* __restrict__ g_o,
    const float* __restrict__ b_o, float* __restrict__ outp, int pos0) {
  constexpr int ROWS = INH / 8;
  const int w = threadIdx.x >> 6;
  const int l = threadIdx.x & 63;
  const int o = l >> 1;
  const int p = blockIdx.x;
  const int posg = pos0 + p;
  const int xaddr = ((l ^ 32) << 2);  // bpermute byte addr for lane^32
  const __half* ug = u + (size_t)p * INH * 512 + (size_t)w * ROWS * 512 + l * 8;

  __shared__ float red_s[8][512];

#define UNPACK(q, f)                                            \
  {                                                             \
    float2 f0 = __half22float2(*(const __half2*)&(q).x);        \
    float2 f1 = __half22float2(*(const __half2*)&(q).y);        \
    float2 f2 = __half22float2(*(const __half2*)&(q).z);        \
    float2 f3 = __half22float2(*(const __half2*)&(q).w);        \
    f[0] = f0.x; f[1] = f0.y; f[2] = f1.x; f[3] = f1.y;         \
    f[4] = f2.x; f[5] = f2.y; f[6] = f3.x; f[7] = f3.y;         \
  }

  // ---- pass A (iter 1): c is constant -> row-sum (streamed)
  float s8[8];
#pragma unroll
  for (int k = 0; k < 8; k++) s8[k] = 0.f;
#pragma unroll 4
  for (int r = 0; r < ROWS; r++) {
    uint4 q = *(const uint4*)(ug + (size_t)r * 512);
    float u8[8];
    UNPACK(q, u8);
#pragma unroll
    for (int k = 0; k < 8; k++) s8[k] += u8[k];
  }
  // cross-wave reduce via LDS
  *(float4*)&red_s[w][l * 8]     = make_float4(s8[0], s8[1], s8[2], s8[3]);
  *(float4*)&red_s[w][l * 8 + 4] = make_float4(s8[4], s8[5], s8[6], s8[7]);
  __syncthreads();
#pragma unroll
  for (int k = 0; k < 8; k++) s8[k] = 0.f;
#pragma unroll
  for (int w2 = 0; w2 < 8; w2++) {
    float4 a = *(const float4*)&red_s[w2][l * 8];
    float4 b = *(const float4*)&red_s[w2][l * 8 + 4];
    s8[0] += a.x; s8[1] += a.y; s8[2] += a.z; s8[3] += a.w;
    s8[4] += b.x; s8[5] += b.y; s8[6] += b.z; s8[7] += b.w;
  }
  const float c1 = MASK ? (o == 0 ? 0.f : (1.f / 31.f)) : (1.f / 32.f);
  float vd[8], vout[8];
  {
    float sn = 0.f;
#pragma unroll
    for (int k = 0; k < 8; k++) { s8[k] *= c1; sn += s8[k] * s8[k]; }
    sn = dpp_add<DPP_XOR1>(sn);
    float f = (sn / (1.f + sn)) * rsqrtf(sn + 1e-9f);
#pragma unroll
    for (int k = 0; k < 8; k++) vd[k] = s8[k] * f;  // vd = v1
  }

  // ---- passes B, C (iters 2, 3). pass C dots against v1+v2 (b telescopes).
#pragma unroll
  for (int iter = 0; iter < 2; iter++) {
    float sacc[8];
#pragma unroll
    for (int k = 0; k < 8; k++) sacc[k] = 0.f;
#pragma unroll 2
    for (int r = 0; r < ROWS; r++) {
      uint4 q = *(const uint4*)(ug + (size_t)r * 512);
      float u8[8];
      UNPACK(q, u8);
      float a = u8[0] * vd[0];
#pragma unroll
      for (int k = 1; k < 8; k++) a = fmaf(u8[k], vd[k], a);
      a = dpp_add<DPP_XOR1>(a);              // full dot over d=16 (pair)
      // softmax over o, no max-subtract (|a| ~ O(1), fp32 exp safe)
      float e = (MASK && o == 0) ? 0.f : __expf(a);
      // denominator: full 64-lane sum (each o counted twice)
      float ss = dpp_add<DPP_XOR1>(e);
      ss = dpp_add<DPP_XOR2>(ss);
      ss = dpp_add<DPP_ROR4>(ss);
      ss = dpp_add<DPP_ROR8>(ss);            // row(16) total
      ss += swz_xor16(ss);                   // 32-lane total
      ss += bperm(xaddr, ss);                // 64-lane total = 2*sum_o e
      float c = __fdividef(e + e, ss);
#pragma unroll
      for (int k = 0; k < 8; k++) sacc[k] = fmaf(c, u8[k], sacc[k]);
    }
    // cross-wave reduce (guard, write, sync, read)
    __syncthreads();
    *(float4*)&red_s[w][l * 8]     = make_float4(sacc[0], sacc[1], sacc[2], sacc[3]);
    *(float4*)&red_s[w][l * 8 + 4] = make_float4(sacc[4], sacc[5], sacc[6], sacc[7]);
    __syncthreads();
#pragma unroll
    for (int k = 0; k < 8; k++) sacc[k] = 0.f;
#pragma unroll
    for (int w2 = 0; w2 < 8; w2++) {
      float4 a = *(const float4*)&red_s[w2][l * 8];
      float4 b = *(const float4*)&red_s[w2][l * 8 + 4];
      sacc[0] += a.x; sacc[1] += a.y; sacc[2] += a.z; sacc[3] += a.w;
      sacc[4] += b.x; sacc[5] += b.y; sacc[6] += b.z; sacc[7] += b.w;
    }
    float sn = 0.f;
#pragma unroll
    for (int k = 0; k < 8; k++) sn += sacc[k] * sacc[k];
    sn = dpp_add<DPP_XOR1>(sn);
    float f = (sn / (1.f + sn)) * rsqrtf(sn + 1e-9f);
#pragma unroll
    for (int k = 0; k < 8; k++) {
      vout[k] = sacc[k] * f;
      vd[k] += vout[k];                      // vd becomes v1+v2 for pass C
    }
  }

  // ---- epilogue (identical in every wave; wave 0 writes): LN over 512
  float s1 = 0.f, s2 = 0.f;
#pragma unroll
  for (int k = 0; k < 8; k++) { s1 += vout[k]; s2 += vout[k] * vout[k]; }
  for (int m = 1; m < 64; m <<= 1) { s1 += __shfl_xor(s1, m); s2 += __shfl_xor(s2, m); }
  float mean = s1 * (1.f / 512.f);
  float var = s2 * (1.f / 512.f) - mean * mean;
  float rstd = rsqrtf(var + 1e-3f);
  const float4 g0 = *(const float4*)(g + 8 * l);
  const float4 g1 = *(const float4*)(g + 8 * l + 4);
  const float4 be0 = *(const float4*)(be + 8 * l);
  const float4 be1 = *(const float4*)(be + 8 * l + 4);
  float nv[8];
  nv[0] = g0.x * (vout[0] - mean) * rstd + be0.x;
  nv[1] = g0.y * (vout[1] - mean) * rstd + be0.y;
  nv[2] = g0.z * (vout[2] - mean) * rstd + be0.z;
  nv[3] = g0.w * (vout[3] - mean) * rstd + be0.w;
  nv[4] = g1.x * (vout[4] - mean) * rstd + be1.x;
  nv[5] = g1.y * (vout[5] - mean) * rstd + be1.y;
  nv[6] = g1.z * (vout[6] - mean) * rstd + be1.z;
  nv[7] = g1.w * (vout[7] - mean) * rstd + be1.w;

  if (!FINAL) {
    if (w == 0) {
      float4 w0 = {nv[0], nv[1], nv[2], nv[3]};
      float4 w1 = {nv[4], nv[5], nv[6], nv[7]};
      float* op = outp + (size_t)posg * 512 + 8 * l;
      *(float4*)op = w0; *(float4*)(op + 4) = w1;
    }
  } else {
    float l2 = 0.f;
#pragma unroll
    for (int k = 0; k < 8; k++) l2 += nv[k] * nv[k];
    l2 = dpp_add<DPP_XOR1>(l2);
    float len = sqrtf(l2 + 1e-9f);
    float a1 = len, a2 = len * len;
    for (int m = 1; m < 64; m <<= 1) { a1 += __shfl_xor(a1, m); a2 += __shfl_xor(a2, m); }
    float mm = a1 * (1.f / 64.f);            // each o counted twice -> /64
    float vv = a2 * (1.f / 64.f) - mm * mm;
    if (w == 0 && (l & 1) == 0)
      outp[(size_t)posg * 32 + o] = g_o[o] * (len - mm) * rsqrtf(vv + 1e-3f) + b_o[o];
  }
#undef UNPACK
}

extern "C" void kernel_launch(void* const* d_in, const int* in_sizes, int n_in,
                              void* d_out, int out_size, void* d_ws, size_t ws_size,
                              hipStream_t stream) {
  const float* x    = (const float*)d_in[0];
  const float* W0   = (const float*)d_in[1];
  const float* B0   = (const float*)d_in[2];
  const float* W1   = (const float*)d_in[3];
  const float* B1   = (const float*)d_in[4];
  const float* g_i  = (const float*)d_in[5];
  const float* b_i  = (const float*)d_in[6];
  const float* g_m0 = (const float*)d_in[7];
  const float* b_m0 = (const float*)d_in[8];
  const float* g_m1 = (const float*)d_in[9];
  const float* b_m1 = (const float*)d_in[10];
  const float* g_o  = (const float*)d_in[11];
  const float* b_o  = (const float*)d_in[12];
  float* out = (float*)d_out;

  char* ws = (char*)d_ws;
  float* emb0 = (float*)ws;                       // 1 MB
  float* emb1 = (float*)(ws + (1 << 20));         // 2 MB
  __half* ubuf = (__half*)(ws + (4 << 20));       // chunked u_hat

  size_t avail = ws_size > (size_t)(4 << 20) ? ws_size - (size_t)(4 << 20) : 0;
  int chunk = 1024;
  while (chunk > 64 && (size_t)chunk * 163840 > avail) chunk >>= 1;

  prep_kernel<<<NPOS, 256, 0, stream>>>(x, g_i, b_i, emb0);

  for (int p0 = 0; p0 < NPOS; p0 += chunk) {
    int cp = (NPOS - p0 < chunk) ? (NPOS - p0) : chunk;
    einsum_kernel<80, 16, 256><<<dim3(80, cp / 64), 512, 0, stream>>>(W0, B0, emb0, ubuf, p0);
    route_kernel<80, false, false><<<cp, 512, 0, stream>>>(ubuf, g_m0, b_m0, nullptr, nullptr, emb1, p0);
  }
  for (int p0 = 0; p0 < NPOS; p0 += chunk) {
    int cp = (NPOS - p0 < chunk) ? (NPOS - p0) : chunk;
    einsum_kernel<160, 32, 512><<<dim3(160, cp / 64), 512, 0, stream>>>(W1, B1, emb1, ubuf, p0);
    route_kernel<160, true, true><<<cp, 512, 0, stream>>>(ubuf, g_m1, b_m1, g_o, b_o, out, p0);
  }
}